// Round 5
// baseline (307.519 us; speedup 1.0000x reference)
//
#include <hip/hip_runtime.h>

typedef __bf16 bf16x8 __attribute__((ext_vector_type(8)));
typedef float f32x4 __attribute__((ext_vector_type(4)));
typedef unsigned int u32x4 __attribute__((ext_vector_type(4)));
typedef unsigned int u32x2 __attribute__((ext_vector_type(2)));
typedef unsigned short u16x8 __attribute__((ext_vector_type(8)));

#define MFMA_BF16(a, b, c) __builtin_amdgcn_mfma_f32_16x16x32_bf16((a), (b), (c), 0, 0, 0)

// 0.125 (1/sqrt(64)) * log2(e): folded into Q so softmax uses raw exp2
#define QSCALE 0.18033688011112043f

__device__ __forceinline__ unsigned short f2bf(float f) {
    unsigned int u = __builtin_bit_cast(unsigned int, f);
    u += 0x7FFFu + ((u >> 16) & 1u);
    return (unsigned short)(u >> 16);
}

// manual RNE pack (bit-identical to f2bf pairs) — numerically sensitive V path stays RNE.
__device__ __forceinline__ unsigned int pack_bf16_rne(float a, float b) {
    unsigned int ua = __builtin_bit_cast(unsigned int, a);
    unsigned int ub = __builtin_bit_cast(unsigned int, b);
    ua += 0x7FFFu + ((ua >> 16) & 1u);
    ub += 0x7FFFu + ((ub >> 16) & 1u);
    return __builtin_amdgcn_perm(ub, ua, 0x07060302);
}

// cheap pack for P (values in [0,1], self-normalizing) — validated earlier
#if __has_builtin(__builtin_amdgcn_cvt_pk_bf16_f32)
typedef __bf16 bf16x2 __attribute__((ext_vector_type(2)));
__device__ __forceinline__ unsigned int pack_bf16(float a, float b) {
    return __builtin_bit_cast(unsigned int, __builtin_amdgcn_cvt_pk_bf16_f32(a, b));
}
#else
__device__ __forceinline__ unsigned int pack_bf16(float a, float b) {
    return pack_bf16_rne(a, b);
}
#endif

#if __has_builtin(__builtin_amdgcn_exp2f)
__device__ __forceinline__ float fast_exp2(float x) { return __builtin_amdgcn_exp2f(x); }
#else
__device__ __forceinline__ float fast_exp2(float x) { return exp2f(x); }
#endif

__device__ __forceinline__ bf16x8 ldfrag(const unsigned short* p) {
    return __builtin_bit_cast(bf16x8, *(const u32x4*)p);
}

// async global->LDS, 16B per lane; LDS dst = wave-uniform base + lane*16B
typedef const __attribute__((address_space(1))) void* gas_t;
typedef __attribute__((address_space(3))) void* las_t;
__device__ __forceinline__ void dma16(const unsigned short* g, unsigned short* l) {
    __builtin_amdgcn_global_load_lds((gas_t)(const void*)g, (las_t)(void*)l, 16, 0, 0);
}

// drain this wave's outstanding DMA/LDS ops, then block barrier.
__device__ __forceinline__ void pipeline_barrier() {
    __builtin_amdgcn_s_waitcnt(0);
    __syncthreads();
}

// ---------------- conversion kernels ----------------

__global__ void cvt_x_kernel(const float* __restrict__ in, unsigned short* __restrict__ out) {
    long long t = (long long)blockIdx.x * 256 + threadIdx.x;
    const f32x4* p = (const f32x4*)in + t * 2;
    f32x4 v0 = p[0], v1 = p[1];
    u16x8 o;
    o[0] = f2bf(v0[0]); o[1] = f2bf(v0[1]); o[2] = f2bf(v0[2]); o[3] = f2bf(v0[3]);
    o[4] = f2bf(v1[0]); o[5] = f2bf(v1[1]); o[6] = f2bf(v1[2]); o[7] = f2bf(v1[3]);
    *((u16x8*)out + t) = o;
}

__global__ void cvt_wqkvT_kernel(const float* __restrict__ Wq, const float* __restrict__ Wk,
                                 const float* __restrict__ Wv, unsigned short* __restrict__ WT) {
    int n = blockIdx.x * 256 + threadIdx.x;
    int d0 = blockIdx.y * 8;
    int proj = n >> 10, rem = n & 1023, h = rem >> 6, e = rem & 63;
    const float* W = (proj == 0) ? Wq : (proj == 1) ? Wk : Wv;
    const float* src = W + (size_t)h * 65536 + (size_t)d0 * 64 + e;
    u16x8 o;
#pragma unroll
    for (int j = 0; j < 8; j++) o[j] = f2bf(src[j * 64]);
    *(u16x8*)(WT + (size_t)n * 1024 + d0) = o;
}

__global__ void cvt_woT_kernel(const float* __restrict__ Wo, unsigned short* __restrict__ WoT) {
    int n = blockIdx.x * 256 + threadIdx.x;
    int d0 = blockIdx.y * 8;
    const float* src = Wo + (size_t)d0 * 1024 + n;
    u16x8 o;
#pragma unroll
    for (int j = 0; j < 8; j++) o[j] = f2bf(src[j * 1024]);
    *(u16x8*)(WoT + (size_t)n * 1024 + d0) = o;
}

// ---------------- GEMM kernels: single-barrier double-buffered DMA pipeline ----------------
// LDS: [2][128][32] u16 per operand; LDS(r,c-chunk) = global(r, c ^ (r&3)); frag chunk = quad ^ (lr&3).
// R8: bijective XCD swizzle (T1) — each XCD gets a contiguous strip of 8 m-panels so its
// A-panels (2 MB) stay L2-resident instead of being re-fetched per n-block.

__global__ __launch_bounds__(256) void gemm_qkv_kernel(
    const unsigned short* __restrict__ A, const unsigned short* __restrict__ BT,
    const float* __restrict__ bq, const float* __restrict__ bk, const float* __restrict__ bv,
    unsigned short* __restrict__ Qo, unsigned short* __restrict__ Ko, unsigned short* __restrict__ VTo) {
    __shared__ unsigned short As[2 * 128 * 32];
    __shared__ unsigned short Bs[2 * 128 * 32];
    const int tid = threadIdx.x;
    // XCD swizzle: 1536 blocks = 8 XCD * 192; XCD x handles sid in [x*192, x*192+192)
    // = m-panels [x*8, x*8+8) over all 24 n-blocks (m-major within the strip).
    const int bid = blockIdx.x;
    const int sid = (bid & 7) * 192 + (bid >> 3);
    const int m0 = (sid / 24) * 128, n0 = (sid % 24) * 128;
    const int w = tid >> 6, lane = tid & 63, lr = lane & 15, quad = lane >> 4;
    const int wy = w >> 1, wx = w & 1;
    f32x4 acc[4][4];
#pragma unroll
    for (int i = 0; i < 4; i++)
#pragma unroll
        for (int j = 0; j < 4; j++) acc[i][j] = (f32x4){0.f, 0.f, 0.f, 0.f};
    const int drow = lane >> 2;
    const int dchunk = (lane & 3) ^ (drow & 3);
    const unsigned short* gA = A + (size_t)(m0 + w * 32 + drow) * 1024 + dchunk * 8;
    const unsigned short* gB = BT + (size_t)(n0 + w * 32 + drow) * 1024 + dchunk * 8;
    const int swav = (w * 32) * 32;
    const int fcol = (quad ^ (lr & 3)) * 8;
    // prologue: tile 0 -> buf 0
    dma16(gA, As + swav);
    dma16(gA + 16 * 1024, As + swav + 16 * 32);
    dma16(gB, Bs + swav);
    dma16(gB + 16 * 1024, Bs + swav + 16 * 32);
    for (int k0 = 0; k0 < 1024; k0 += 32) {
        const int cur = (k0 >> 5) & 1;
        const unsigned short* cA = As + cur * 4096;
        const unsigned short* cB = Bs + cur * 4096;
        pipeline_barrier();  // drains this wave's DMA for tile k0; releases buf[cur^1]
        bf16x8 af[4], bfr[4];
#pragma unroll
        for (int i = 0; i < 4; i++) af[i] = ldfrag(cA + (wy * 64 + i * 16 + lr) * 32 + fcol);
#pragma unroll
        for (int j = 0; j < 4; j++) bfr[j] = ldfrag(cB + (wx * 64 + j * 16 + lr) * 32 + fcol);
        if (k0 + 32 < 1024) {  // prefetch tile k0+32 into other buffer
            const int nb = (cur ^ 1) * 4096 + swav;
            dma16(gA + k0 + 32, As + nb);
            dma16(gA + k0 + 32 + 16 * 1024, As + nb + 16 * 32);
            dma16(gB + k0 + 32, Bs + nb);
            dma16(gB + k0 + 32 + 16 * 1024, Bs + nb + 16 * 32);
        }
#pragma unroll
        for (int i = 0; i < 4; i++)
#pragma unroll
            for (int j = 0; j < 4; j++) acc[i][j] = MFMA_BF16(af[i], bfr[j], acc[i][j]);
    }
#pragma unroll
    for (int j = 0; j < 4; j++) {
        int n = n0 + wx * 64 + j * 16 + lr;
        int proj = n >> 10, rem = n & 1023, h = rem >> 6, e = rem & 63;
        if (proj == 2) {
            // V: write transposed [bh, e, s] with packed b64 stores down s (RNE pack!)
            float bb = bv[rem];
#pragma unroll
            for (int i = 0; i < 4; i++) {
                int m = m0 + wy * 64 + i * 16 + quad * 4;
                int batch = m >> 11, s = m & 2047;
                u32x2 pk;
                pk[0] = pack_bf16_rne(acc[i][j][0] + bb, acc[i][j][1] + bb);
                pk[1] = pack_bf16_rne(acc[i][j][2] + bb, acc[i][j][3] + bb);
                *(u32x2*)(VTo + (((size_t)batch * 16 + h) * 64 + e) * 2048 + s) = pk;
            }
        } else {
            const float* bias = (proj == 0) ? bq : bk;
            unsigned short* dst = (proj == 0) ? Qo : Ko;
            float bb = bias[rem];
            float scl = (proj == 0) ? QSCALE : 1.0f;
#pragma unroll
            for (int i = 0; i < 4; i++) {
#pragma unroll
                for (int r = 0; r < 4; r++) {
                    int m = m0 + wy * 64 + i * 16 + quad * 4 + r;
                    int batch = m >> 11, s = m & 2047;
                    dst[(((size_t)batch * 16 + h) * 2048 + s) * 64 + e] = f2bf((acc[i][j][r] + bb) * scl);
                }
            }
        }
    }
}

__global__ __launch_bounds__(256) void gemm_out_kernel(
    const unsigned short* __restrict__ A, const unsigned short* __restrict__ BT,
    const float* __restrict__ bo, float* __restrict__ out) {
    __shared__ unsigned short As[2 * 128 * 32];
    __shared__ unsigned short Bs[2 * 128 * 32];
    const int tid = threadIdx.x;
    // XCD swizzle: 512 blocks = 8 XCD * 64; XCD x -> m-panels [x*8, x*8+8) over 8 n-blocks.
    const int bid = blockIdx.x;
    const int sid = (bid & 7) * 64 + (bid >> 3);
    const int m0 = (sid >> 3) * 128, n0 = (sid & 7) * 128;
    const int w = tid >> 6, lane = tid & 63, lr = lane & 15, quad = lane >> 4;
    const int wy = w >> 1, wx = w & 1;
    f32x4 acc[4][4];
#pragma unroll
    for (int i = 0; i < 4; i++)
#pragma unroll
        for (int j = 0; j < 4; j++) acc[i][j] = (f32x4){0.f, 0.f, 0.f, 0.f};
    const int drow = lane >> 2;
    const int dchunk = (lane & 3) ^ (drow & 3);
    const unsigned short* gA = A + (size_t)(m0 + w * 32 + drow) * 1024 + dchunk * 8;
    const unsigned short* gB = BT + (size_t)(n0 + w * 32 + drow) * 1024 + dchunk * 8;
    const int swav = (w * 32) * 32;
    const int fcol = (quad ^ (lr & 3)) * 8;
    dma16(gA, As + swav);
    dma16(gA + 16 * 1024, As + swav + 16 * 32);
    dma16(gB, Bs + swav);
    dma16(gB + 16 * 1024, Bs + swav + 16 * 32);
    for (int k0 = 0; k0 < 1024; k0 += 32) {
        const int cur = (k0 >> 5) & 1;
        const unsigned short* cA = As + cur * 4096;
        const unsigned short* cB = Bs + cur * 4096;
        pipeline_barrier();
        bf16x8 af[4], bfr[4];
#pragma unroll
        for (int i = 0; i < 4; i++) af[i] = ldfrag(cA + (wy * 64 + i * 16 + lr) * 32 + fcol);
#pragma unroll
        for (int j = 0; j < 4; j++) bfr[j] = ldfrag(cB + (wx * 64 + j * 16 + lr) * 32 + fcol);
        if (k0 + 32 < 1024) {
            const int nb = (cur ^ 1) * 4096 + swav;
            dma16(gA + k0 + 32, As + nb);
            dma16(gA + k0 + 32 + 16 * 1024, As + nb + 16 * 32);
            dma16(gB + k0 + 32, Bs + nb);
            dma16(gB + k0 + 32 + 16 * 1024, Bs + nb + 16 * 32);
        }
#pragma unroll
        for (int i = 0; i < 4; i++)
#pragma unroll
            for (int j = 0; j < 4; j++) acc[i][j] = MFMA_BF16(af[i], bfr[j], acc[i][j]);
    }
#pragma unroll
    for (int j = 0; j < 4; j++) {
        int n = n0 + wx * 64 + j * 16 + lr;
        float bb = bo[n];
#pragma unroll
        for (int i = 0; i < 4; i++) {
#pragma unroll
            for (int r = 0; r < 4; r++) {
                int m = m0 + wy * 64 + i * 16 + quad * 4 + r;
                out[(size_t)m * 1024 + n] = acc[i][j][r] + bb;
            }
        }
    }
}

// ---------------- flash attention (S^T = K Q^T, no-max softmax, dbuf DMA pipeline) ----------------
// R8: R2 skeleton (K AND V both in the DMA double-buffer — R3/R4 falsified all direct-load
// variants) + cross-tile PV pipelining: PV(t-1) is deferred into iteration t, placed AFTER
// QK^T(t) so its register-only MFMAs interleave with QK^T's exp2/pack VALU stream, and the
// pa lgkm wait hides under a full QK^T phase. pa(t-1) is read from Ps at the TOP of iter t,
// BEFORE QK^T(t)'s aliasing P-writes (same-wave DS ops are in-order; compiler preserves
// load-before-aliasing-store). V-frags of t-1 are held in regs across the barrier.
// P buffer: wave-private 64x64 u16, 16B-chunk XOR swizzle (chunk ^ (row&7)).
// K/V tiles: [2][64][64] u16, source-swizzled: LDS(r,c) = global(r, c ^ (r&7));
// frag reads use chunk (kc*4+quad) ^ (lr&7) -> <=2-way (free) b128.
__global__ __launch_bounds__(256, 2) void attn_fa_kernel(
    const unsigned short* __restrict__ Q, const unsigned short* __restrict__ K,
    const unsigned short* __restrict__ VT, unsigned short* __restrict__ Out) {
    __shared__ unsigned short Ks[2 * 64 * 64];
    __shared__ unsigned short Vs[2 * 64 * 64];
    __shared__ unsigned short Ps[256 * 64];  // wave-private 64-row P regions, XOR-swizzled
    const int bh = blockIdx.x;               // bh on x: all 8 q-blocks of a head share an XCD (id%8)
    const int q0 = blockIdx.y * 256;
    const int tid = threadIdx.x;
    const int w = tid >> 6, lane = tid & 63, lr = lane & 15, quad = lane >> 4;
    const unsigned short* Qh = Q + (size_t)bh * 2048 * 64;
    const unsigned short* Kh = K + (size_t)bh * 2048 * 64;
    const unsigned short* Vh = VT + (size_t)bh * 64 * 2048;

    const f32x4 ZERO4 = {0.f, 0.f, 0.f, 0.f};

    // DMA setup: wave w covers K/V rows w*16 .. w*16+15 (2 instrs of 8 rows each)
    const int drow = lane >> 3;
    const int dchunk = (lane & 7) ^ drow;
    const unsigned short* gK = Kh + (size_t)(w * 16 + drow) * 64 + dchunk * 8;
    const unsigned short* gV = Vh + (size_t)(w * 16 + drow) * 2048 + dchunk * 8;
    const int swav = (w * 16) * 64;
    // prologue: tile 0 -> buf 0
    dma16(gK, Ks + swav);
    dma16(gK + 8 * 64, Ks + swav + 8 * 64);
    dma16(gV, Vs + swav);
    dma16(gV + 8 * 2048, Vs + swav + 8 * 64);

    // Q fragments direct from global (one-time load; stays in regs)
    bf16x8 qb[4][2];  // [q-16-group][kc]
#pragma unroll
    for (int nt = 0; nt < 4; nt++)
#pragma unroll
        for (int kc = 0; kc < 2; kc++)
            qb[nt][kc] = ldfrag(Qh + (size_t)(q0 + w * 64 + nt * 16 + lr) * 64 + kc * 32 + quad * 8);

    f32x4 o[4][4];
#pragma unroll
    for (int i = 0; i < 4; i++)
#pragma unroll
        for (int j = 0; j < 4; j++) o[i][j] = ZERO4;
    float lp[4] = {0.f, 0.f, 0.f, 0.f};

    unsigned short* const Pw = Ps + (w * 64) * 64;  // this wave's private P rows
    const int swzb = lr & 7;                        // row&7 for all P rows this lane touches

    bf16x8 vbp[2][4];  // V fragments of the PREVIOUS tile (held across the barrier)
    bf16x8 pap[2][4];  // P fragments of the PREVIOUS tile

    // QK^T + softmax for the tile staged in cK: MFMA pair -> exp2 -> pack -> P write.
    auto qkt_softmax = [&](const unsigned short* cK) {
        bf16x8 ka[2][4];
#pragma unroll
        for (int kc = 0; kc < 2; kc++)
#pragma unroll
            for (int mt = 0; mt < 4; mt++)
                ka[kc][mt] = ldfrag(cK + (mt * 16 + lr) * 64 + ((kc * 4 + quad) ^ swzb) * 8);
#pragma unroll
        for (int mt = 0; mt < 4; mt++) {
            f32x4 sc[4];
#pragma unroll
            for (int nt = 0; nt < 4; nt++) {
                f32x4 z = ZERO4;
                sc[nt] = MFMA_BF16(ka[0][mt], qb[nt][0], z);
                sc[nt] = MFMA_BF16(ka[1][mt], qb[nt][1], sc[nt]);
            }
#pragma unroll
            for (int nt = 0; nt < 4; nt++) {
                float p0 = fast_exp2(sc[nt][0]);
                float p1 = fast_exp2(sc[nt][1]);
                float p2 = fast_exp2(sc[nt][2]);
                float p3 = fast_exp2(sc[nt][3]);
                lp[nt] += (p0 + p1) + (p2 + p3);
                u32x2 pk;
                pk[0] = pack_bf16(p0, p1);
                pk[1] = pack_bf16(p2, p3);
                // row = nt*16+lr; 16B chunk (2*mt + quad/2) swizzled by row&7; 8B half = quad&1
                *(u32x2*)(Pw + (nt * 16 + lr) * 64 + ((2 * mt + (quad >> 1)) ^ swzb) * 8 +
                          (quad & 1) * 4) = pk;
            }
        }
    };
    auto read_pa = [&]() {
#pragma unroll
        for (int kc = 0; kc < 2; kc++) {
            const int fc = ((kc * 4 + quad) ^ swzb) * 8;
#pragma unroll
            for (int g = 0; g < 4; g++) pap[kc][g] = ldfrag(Pw + (g * 16 + lr) * 64 + fc);
        }
    };
    auto read_vb = [&](const unsigned short* cV) {
#pragma unroll
        for (int kc = 0; kc < 2; kc++) {
            const int fc = ((kc * 4 + quad) ^ swzb) * 8;
#pragma unroll
            for (int et = 0; et < 4; et++) vbp[kc][et] = ldfrag(cV + (et * 16 + lr) * 64 + fc);
        }
    };
    auto do_pv = [&]() {
#pragma unroll
        for (int kc = 0; kc < 2; kc++)
#pragma unroll
            for (int g = 0; g < 4; g++) {
                o[g][0] = MFMA_BF16(pap[kc][g], vbp[kc][0], o[g][0]);
                o[g][1] = MFMA_BF16(pap[kc][g], vbp[kc][1], o[g][1]);
                o[g][2] = MFMA_BF16(pap[kc][g], vbp[kc][2], o[g][2]);
                o[g][3] = MFMA_BF16(pap[kc][g], vbp[kc][3], o[g][3]);
            }
    };

    // ---- peeled tile 0 ----
    pipeline_barrier();
    {
        const int nb = 4096 + swav;  // prefetch tile 1 -> buf 1
        dma16(gK + 64 * 64, Ks + nb);
        dma16(gK + 64 * 64 + 8 * 64, Ks + nb + 8 * 64);
        dma16(gV + 64, Vs + nb);
        dma16(gV + 64 + 8 * 2048, Vs + nb + 8 * 64);
        qkt_softmax(Ks);
        read_vb(Vs);  // V(0) -> regs, survives the next barrier
    }

    // ---- main loop: iter t computes QK^T(t) and the DEFERRED PV(t-1) ----
    for (int t0 = 64; t0 < 2048; t0 += 64) {
        const int cur = (t0 >> 6) & 1;
        const unsigned short* cK = Ks + cur * 4096;
        const unsigned short* cV = Vs + cur * 4096;
        pipeline_barrier();  // drains this tile's DMA; releases other buffer
        read_pa();           // P(t-1) from Ps — BEFORE QK^T(t) overwrites it (in-order DS)
        if (t0 + 64 < 2048) {  // prefetch next tile into other buffer
            const int nb = (cur ^ 1) * 4096 + swav;
            dma16(gK + (size_t)(t0 + 64) * 64, Ks + nb);
            dma16(gK + (size_t)(t0 + 64) * 64 + 8 * 64, Ks + nb + 8 * 64);
            dma16(gV + t0 + 64, Vs + nb);
            dma16(gV + t0 + 64 + 8 * 2048, Vs + nb + 8 * 64);
        }
        qkt_softmax(cK);  // writes P(t)
        do_pv();          // PV(t-1): register-only MFMAs, interleave with exp2 above
        read_vb(cV);      // V(t) -> regs (after PV released vbp)
    }
    // ---- epilogue: PV for the last tile ----
    read_pa();
    do_pv();

    // final denominator: reduce across the 4 quads
#pragma unroll
    for (int g = 0; g < 4; g++) {
        float l = lp[g];
        l += __shfl_xor(l, 16, 64);
        l += __shfl_xor(l, 32, 64);
        lp[g] = l;
    }

    // normalize + write attn [B,S,H*E] bf16
    const int h = bh & 15, b = bh >> 4;
#pragma unroll
    for (int g = 0; g < 4; g++) {
#pragma unroll
        for (int r = 0; r < 4; r++) {
            float l = __shfl(lp[g], quad * 4 + r, 16);
            float inv = 1.0f / l;
            int s = q0 + w * 64 + g * 16 + quad * 4 + r;
#pragma unroll
            for (int et = 0; et < 4; et++) {
                int col = h * 64 + et * 16 + lr;
                Out[((size_t)(b * 2048 + s)) * 1024 + col] = f2bf(o[g][et][r] * inv);
            }
        }
    }
}

// ---------------- launch ----------------

extern "C" void kernel_launch(void* const* d_in, const int* in_sizes, int n_in,
                              void* d_out, int out_size, void* d_ws, size_t ws_size,
                              hipStream_t stream) {
    const float* x  = (const float*)d_in[0];
    const float* Wq = (const float*)d_in[1];
    const float* bq = (const float*)d_in[2];
    const float* Wk = (const float*)d_in[3];
    const float* bk = (const float*)d_in[4];
    const float* Wv = (const float*)d_in[5];
    const float* bv = (const float*)d_in[6];
    const float* Wo = (const float*)d_in[7];
    const float* bo = (const float*)d_in[8];
    float* out = (float*)d_out;

    char* ws = (char*)d_ws;
    unsigned short* xb    = (unsigned short*)(ws);              // 16 MiB; reused as attn buffer
    unsigned short* WqkvT = (unsigned short*)(ws + 16777216);   // 6 MiB
    unsigned short* WoT   = (unsigned short*)(ws + 23068672);   // 2 MiB
    unsigned short* Qb    = (unsigned short*)(ws + 25165824);   // 16 MiB
    unsigned short* Kb    = (unsigned short*)(ws + 41943040);   // 16 MiB
    unsigned short* VTb   = (unsigned short*)(ws + 58720256);   // 16 MiB (total 72 MiB)
    unsigned short* attn  = xb;  // xb is dead after gemm_qkv

    cvt_x_kernel<<<dim3(4096), dim3(256), 0, stream>>>(x, xb);
    cvt_wqkvT_kernel<<<dim3(12, 128), dim3(256), 0, stream>>>(Wq, Wk, Wv, WqkvT);
    cvt_woT_kernel<<<dim3(4, 128), dim3(256), 0, stream>>>(Wo, WoT);
    gemm_qkv_kernel<<<dim3(1536), dim3(256), 0, stream>>>(xb, WqkvT, bq, bk, bv, Qb, Kb, VTb);
    attn_fa_kernel<<<dim3(64, 8), dim3(256), 0, stream>>>(Qb, Kb, VTb, attn);
    gemm_out_kernel<<<dim3(512), dim3(256), 0, stream>>>(attn, WoT, bo, out);
}

// Round 6
// 299.195 us; speedup vs baseline: 1.0278x; 1.0278x over previous
//
#include <hip/hip_runtime.h>

typedef __bf16 bf16x8 __attribute__((ext_vector_type(8)));
typedef float f32x4 __attribute__((ext_vector_type(4)));
typedef unsigned int u32x4 __attribute__((ext_vector_type(4)));
typedef unsigned int u32x2 __attribute__((ext_vector_type(2)));
typedef unsigned short u16x8 __attribute__((ext_vector_type(8)));

#define MFMA_BF16(a, b, c) __builtin_amdgcn_mfma_f32_16x16x32_bf16((a), (b), (c), 0, 0, 0)

// 0.125 (1/sqrt(64)) * log2(e): folded into Q so softmax uses raw exp2
#define QSCALE 0.18033688011112043f

__device__ __forceinline__ unsigned short f2bf(float f) {
    unsigned int u = __builtin_bit_cast(unsigned int, f);
    u += 0x7FFFu + ((u >> 16) & 1u);
    return (unsigned short)(u >> 16);
}

// manual RNE pack (bit-identical to f2bf pairs) — numerically sensitive V path stays RNE.
__device__ __forceinline__ unsigned int pack_bf16_rne(float a, float b) {
    unsigned int ua = __builtin_bit_cast(unsigned int, a);
    unsigned int ub = __builtin_bit_cast(unsigned int, b);
    ua += 0x7FFFu + ((ua >> 16) & 1u);
    ub += 0x7FFFu + ((ub >> 16) & 1u);
    return __builtin_amdgcn_perm(ub, ua, 0x07060302);
}

// cheap pack for P (values in [0,1], self-normalizing) — validated earlier
#if __has_builtin(__builtin_amdgcn_cvt_pk_bf16_f32)
typedef __bf16 bf16x2 __attribute__((ext_vector_type(2)));
__device__ __forceinline__ unsigned int pack_bf16(float a, float b) {
    return __builtin_bit_cast(unsigned int, __builtin_amdgcn_cvt_pk_bf16_f32(a, b));
}
#else
__device__ __forceinline__ unsigned int pack_bf16(float a, float b) {
    return pack_bf16_rne(a, b);
}
#endif

#if __has_builtin(__builtin_amdgcn_exp2f)
__device__ __forceinline__ float fast_exp2(float x) { return __builtin_amdgcn_exp2f(x); }
#else
__device__ __forceinline__ float fast_exp2(float x) { return exp2f(x); }
#endif

__device__ __forceinline__ bf16x8 ldfrag(const unsigned short* p) {
    return __builtin_bit_cast(bf16x8, *(const u32x4*)p);
}

// async global->LDS, 16B per lane; LDS dst = wave-uniform base + lane*16B
typedef const __attribute__((address_space(1))) void* gas_t;
typedef __attribute__((address_space(3))) void* las_t;
__device__ __forceinline__ void dma16(const unsigned short* g, unsigned short* l) {
    __builtin_amdgcn_global_load_lds((gas_t)(const void*)g, (las_t)(void*)l, 16, 0, 0);
}

// drain this wave's outstanding DMA/LDS ops, then block barrier.
__device__ __forceinline__ void pipeline_barrier() {
    __builtin_amdgcn_s_waitcnt(0);
    __syncthreads();
}

// ---------------- conversion kernels ----------------

__global__ void cvt_x_kernel(const float* __restrict__ in, unsigned short* __restrict__ out) {
    long long t = (long long)blockIdx.x * 256 + threadIdx.x;
    const f32x4* p = (const f32x4*)in + t * 2;
    f32x4 v0 = p[0], v1 = p[1];
    u16x8 o;
    o[0] = f2bf(v0[0]); o[1] = f2bf(v0[1]); o[2] = f2bf(v0[2]); o[3] = f2bf(v0[3]);
    o[4] = f2bf(v1[0]); o[5] = f2bf(v1[1]); o[6] = f2bf(v1[2]); o[7] = f2bf(v1[3]);
    *((u16x8*)out + t) = o;
}

__global__ void cvt_wqkvT_kernel(const float* __restrict__ Wq, const float* __restrict__ Wk,
                                 const float* __restrict__ Wv, unsigned short* __restrict__ WT) {
    int n = blockIdx.x * 256 + threadIdx.x;
    int d0 = blockIdx.y * 8;
    int proj = n >> 10, rem = n & 1023, h = rem >> 6, e = rem & 63;
    const float* W = (proj == 0) ? Wq : (proj == 1) ? Wk : Wv;
    const float* src = W + (size_t)h * 65536 + (size_t)d0 * 64 + e;
    u16x8 o;
#pragma unroll
    for (int j = 0; j < 8; j++) o[j] = f2bf(src[j * 64]);
    *(u16x8*)(WT + (size_t)n * 1024 + d0) = o;
}

__global__ void cvt_woT_kernel(const float* __restrict__ Wo, unsigned short* __restrict__ WoT) {
    int n = blockIdx.x * 256 + threadIdx.x;
    int d0 = blockIdx.y * 8;
    const float* src = Wo + (size_t)d0 * 1024 + n;
    u16x8 o;
#pragma unroll
    for (int j = 0; j < 8; j++) o[j] = f2bf(src[j * 1024]);
    *(u16x8*)(WoT + (size_t)n * 1024 + d0) = o;
}

// ---------------- GEMM kernels: single-barrier double-buffered DMA pipeline ----------------
// LDS: [2][128][32] u16 per operand; LDS(r,c-chunk) = global(r, c ^ (r&3)); frag chunk = quad ^ (lr&3).
// (R2 form: dim3(24,64)/(8,64) grids — R5's XCD swizzle showed no gain and was reverted.)

__global__ __launch_bounds__(256) void gemm_qkv_kernel(
    const unsigned short* __restrict__ A, const unsigned short* __restrict__ BT,
    const float* __restrict__ bq, const float* __restrict__ bk, const float* __restrict__ bv,
    unsigned short* __restrict__ Qo, unsigned short* __restrict__ Ko, unsigned short* __restrict__ VTo) {
    __shared__ unsigned short As[2 * 128 * 32];
    __shared__ unsigned short Bs[2 * 128 * 32];
    const int tid = threadIdx.x;
    const int m0 = blockIdx.y * 128, n0 = blockIdx.x * 128;
    const int w = tid >> 6, lane = tid & 63, lr = lane & 15, quad = lane >> 4;
    const int wy = w >> 1, wx = w & 1;
    f32x4 acc[4][4];
#pragma unroll
    for (int i = 0; i < 4; i++)
#pragma unroll
        for (int j = 0; j < 4; j++) acc[i][j] = (f32x4){0.f, 0.f, 0.f, 0.f};
    const int drow = lane >> 2;
    const int dchunk = (lane & 3) ^ (drow & 3);
    const unsigned short* gA = A + (size_t)(m0 + w * 32 + drow) * 1024 + dchunk * 8;
    const unsigned short* gB = BT + (size_t)(n0 + w * 32 + drow) * 1024 + dchunk * 8;
    const int swav = (w * 32) * 32;
    const int fcol = (quad ^ (lr & 3)) * 8;
    // prologue: tile 0 -> buf 0
    dma16(gA, As + swav);
    dma16(gA + 16 * 1024, As + swav + 16 * 32);
    dma16(gB, Bs + swav);
    dma16(gB + 16 * 1024, Bs + swav + 16 * 32);
    for (int k0 = 0; k0 < 1024; k0 += 32) {
        const int cur = (k0 >> 5) & 1;
        const unsigned short* cA = As + cur * 4096;
        const unsigned short* cB = Bs + cur * 4096;
        pipeline_barrier();  // drains this wave's DMA for tile k0; releases buf[cur^1]
        bf16x8 af[4], bfr[4];
#pragma unroll
        for (int i = 0; i < 4; i++) af[i] = ldfrag(cA + (wy * 64 + i * 16 + lr) * 32 + fcol);
#pragma unroll
        for (int j = 0; j < 4; j++) bfr[j] = ldfrag(cB + (wx * 64 + j * 16 + lr) * 32 + fcol);
        if (k0 + 32 < 1024) {  // prefetch tile k0+32 into other buffer
            const int nb = (cur ^ 1) * 4096 + swav;
            dma16(gA + k0 + 32, As + nb);
            dma16(gA + k0 + 32 + 16 * 1024, As + nb + 16 * 32);
            dma16(gB + k0 + 32, Bs + nb);
            dma16(gB + k0 + 32 + 16 * 1024, Bs + nb + 16 * 32);
        }
#pragma unroll
        for (int i = 0; i < 4; i++)
#pragma unroll
            for (int j = 0; j < 4; j++) acc[i][j] = MFMA_BF16(af[i], bfr[j], acc[i][j]);
    }
#pragma unroll
    for (int j = 0; j < 4; j++) {
        int n = n0 + wx * 64 + j * 16 + lr;
        int proj = n >> 10, rem = n & 1023, h = rem >> 6, e = rem & 63;
        if (proj == 2) {
            // V: write transposed [bh, e, s] with packed b64 stores down s (RNE pack!)
            float bb = bv[rem];
#pragma unroll
            for (int i = 0; i < 4; i++) {
                int m = m0 + wy * 64 + i * 16 + quad * 4;
                int batch = m >> 11, s = m & 2047;
                u32x2 pk;
                pk[0] = pack_bf16_rne(acc[i][j][0] + bb, acc[i][j][1] + bb);
                pk[1] = pack_bf16_rne(acc[i][j][2] + bb, acc[i][j][3] + bb);
                *(u32x2*)(VTo + (((size_t)batch * 16 + h) * 64 + e) * 2048 + s) = pk;
            }
        } else {
            const float* bias = (proj == 0) ? bq : bk;
            unsigned short* dst = (proj == 0) ? Qo : Ko;
            float bb = bias[rem];
            float scl = (proj == 0) ? QSCALE : 1.0f;
#pragma unroll
            for (int i = 0; i < 4; i++) {
#pragma unroll
                for (int r = 0; r < 4; r++) {
                    int m = m0 + wy * 64 + i * 16 + quad * 4 + r;
                    int batch = m >> 11, s = m & 2047;
                    dst[(((size_t)batch * 16 + h) * 2048 + s) * 64 + e] = f2bf((acc[i][j][r] + bb) * scl);
                }
            }
        }
    }
}

__global__ __launch_bounds__(256) void gemm_out_kernel(
    const unsigned short* __restrict__ A, const unsigned short* __restrict__ BT,
    const float* __restrict__ bo, float* __restrict__ out) {
    __shared__ unsigned short As[2 * 128 * 32];
    __shared__ unsigned short Bs[2 * 128 * 32];
    const int tid = threadIdx.x;
    const int m0 = blockIdx.y * 128, n0 = blockIdx.x * 128;
    const int w = tid >> 6, lane = tid & 63, lr = lane & 15, quad = lane >> 4;
    const int wy = w >> 1, wx = w & 1;
    f32x4 acc[4][4];
#pragma unroll
    for (int i = 0; i < 4; i++)
#pragma unroll
        for (int j = 0; j < 4; j++) acc[i][j] = (f32x4){0.f, 0.f, 0.f, 0.f};
    const int drow = lane >> 2;
    const int dchunk = (lane & 3) ^ (drow & 3);
    const unsigned short* gA = A + (size_t)(m0 + w * 32 + drow) * 1024 + dchunk * 8;
    const unsigned short* gB = BT + (size_t)(n0 + w * 32 + drow) * 1024 + dchunk * 8;
    const int swav = (w * 32) * 32;
    const int fcol = (quad ^ (lr & 3)) * 8;
    dma16(gA, As + swav);
    dma16(gA + 16 * 1024, As + swav + 16 * 32);
    dma16(gB, Bs + swav);
    dma16(gB + 16 * 1024, Bs + swav + 16 * 32);
    for (int k0 = 0; k0 < 1024; k0 += 32) {
        const int cur = (k0 >> 5) & 1;
        const unsigned short* cA = As + cur * 4096;
        const unsigned short* cB = Bs + cur * 4096;
        pipeline_barrier();
        bf16x8 af[4], bfr[4];
#pragma unroll
        for (int i = 0; i < 4; i++) af[i] = ldfrag(cA + (wy * 64 + i * 16 + lr) * 32 + fcol);
#pragma unroll
        for (int j = 0; j < 4; j++) bfr[j] = ldfrag(cB + (wx * 64 + j * 16 + lr) * 32 + fcol);
        if (k0 + 32 < 1024) {
            const int nb = (cur ^ 1) * 4096 + swav;
            dma16(gA + k0 + 32, As + nb);
            dma16(gA + k0 + 32 + 16 * 1024, As + nb + 16 * 32);
            dma16(gB + k0 + 32, Bs + nb);
            dma16(gB + k0 + 32 + 16 * 1024, Bs + nb + 16 * 32);
        }
#pragma unroll
        for (int i = 0; i < 4; i++)
#pragma unroll
            for (int j = 0; j < 4; j++) acc[i][j] = MFMA_BF16(af[i], bfr[j], acc[i][j]);
    }
#pragma unroll
    for (int j = 0; j < 4; j++) {
        int n = n0 + wx * 64 + j * 16 + lr;
        float bb = bo[n];
#pragma unroll
        for (int i = 0; i < 4; i++) {
#pragma unroll
            for (int r = 0; r < 4; r++) {
                int m = m0 + wy * 64 + i * 16 + quad * 4 + r;
                out[(size_t)m * 1024 + n] = acc[i][j][r] + bb;
            }
        }
    }
}

// ---------------- flash attention (S^T = K Q^T, no-max softmax, dbuf DMA pipeline) ----------------
// R9: occupancy attack. R2's per-tile schedule kept EXACTLY (R3/R4/R5 falsified every
// reordering), but the block is re-shaped for 4 resident blocks/CU = 16 waves/CU (50% occ
// cap, was 25%): 128 q-rows/block (32/wave), grid 64x16 = 1024 = exactly 4/CU (no tail).
// LDS cut 64->40 KiB (x4 = 160 = full LDS): K/V dbuf unchanged (32 KiB); P shrinks to
// [128][32] (8 KiB) by processing each 64-t tile as TWO 32-t halves: QK^T(half) -> P
// roundtrip -> PV(half). P aliasing between halves is safe: same-wave DS ordering
// (PV-half0 pa reads precede QK^T-half1 P writes in program order).
// __launch_bounds__(256,4) caps VGPR at 128 (est ~90 live).
// P rows: 32 u16, 4 chunks, XOR swizzle chunk ^ (lr&3) -> same conflict level as R2.
// K/V tiles: [2][64][64] u16, source-swizzled LDS(r,c) = global(r, c ^ (r&7));
// frag reads use chunk (idx) ^ (lr&7) -> <=2-way (free) b128.
__global__ __launch_bounds__(256, 4) void attn_fa_kernel(
    const unsigned short* __restrict__ Q, const unsigned short* __restrict__ K,
    const unsigned short* __restrict__ VT, unsigned short* __restrict__ Out) {
    __shared__ unsigned short Ks[2 * 64 * 64];  // 16 KiB
    __shared__ unsigned short Vs[2 * 64 * 64];  // 16 KiB
    __shared__ unsigned short Ps[128 * 32];     // 8 KiB: wave-private 32x32 P regions
    const int bh = blockIdx.x;                  // bh on x: all 16 q-blocks of a head share an XCD
    const int q0 = blockIdx.y * 128;
    const int tid = threadIdx.x;
    const int w = tid >> 6, lane = tid & 63, lr = lane & 15, quad = lane >> 4;
    const unsigned short* Qh = Q + (size_t)bh * 2048 * 64;
    const unsigned short* Kh = K + (size_t)bh * 2048 * 64;
    const unsigned short* Vh = VT + (size_t)bh * 64 * 2048;

    const f32x4 ZERO4 = {0.f, 0.f, 0.f, 0.f};

    // DMA setup: wave w covers K/V rows w*16 .. w*16+15 (2 instrs of 8 rows each)
    const int drow = lane >> 3;
    const int dchunk = (lane & 7) ^ drow;
    const unsigned short* gK = Kh + (size_t)(w * 16 + drow) * 64 + dchunk * 8;
    const unsigned short* gV = Vh + (size_t)(w * 16 + drow) * 2048 + dchunk * 8;
    const int swav = (w * 16) * 64;
    // prologue: tile 0 -> buf 0
    dma16(gK, Ks + swav);
    dma16(gK + 8 * 64, Ks + swav + 8 * 64);
    dma16(gV, Vs + swav);
    dma16(gV + 8 * 2048, Vs + swav + 8 * 64);

    // Q fragments direct from global (one-time load; stays in regs)
    bf16x8 qb[2][2];  // [q-16-group][kc]
#pragma unroll
    for (int nt = 0; nt < 2; nt++)
#pragma unroll
        for (int kc = 0; kc < 2; kc++)
            qb[nt][kc] = ldfrag(Qh + (size_t)(q0 + w * 32 + nt * 16 + lr) * 64 + kc * 32 + quad * 8);

    f32x4 o[2][4];
#pragma unroll
    for (int i = 0; i < 2; i++)
#pragma unroll
        for (int j = 0; j < 4; j++) o[i][j] = ZERO4;
    float lp[2] = {0.f, 0.f};

    unsigned short* const Pw = Ps + (w * 32) * 32;  // this wave's private P rows (32x32)
    const int swzb = lr & 7;  // K/V chunk swizzle base
    const int swz3 = lr & 3;  // P chunk swizzle base (4-chunk rows)

    for (int t0 = 0; t0 < 2048; t0 += 64) {
        const int cur = (t0 >> 6) & 1;
        const unsigned short* cK = Ks + cur * 4096;
        const unsigned short* cV = Vs + cur * 4096;
        pipeline_barrier();  // drains this tile's DMA; releases other buffer
        if (t0 + 64 < 2048) {  // prefetch next tile into other buffer
            const int nb = (cur ^ 1) * 4096 + swav;
            dma16(gK + (size_t)(t0 + 64) * 64, Ks + nb);
            dma16(gK + (size_t)(t0 + 64) * 64 + 8 * 64, Ks + nb + 8 * 64);
            dma16(gV + t0 + 64, Vs + nb);
            dma16(gV + t0 + 64 + 8 * 2048, Vs + nb + 8 * 64);
        }

#pragma unroll
        for (int half = 0; half < 2; half++) {
            // ---- QK^T half: 32 t-rows (half*32 .. half*32+31) ----
            bf16x8 ka[2][2];
#pragma unroll
            for (int kc = 0; kc < 2; kc++)
#pragma unroll
                for (int mt = 0; mt < 2; mt++)
                    ka[kc][mt] = ldfrag(cK + (half * 32 + mt * 16 + lr) * 64 +
                                        ((kc * 4 + quad) ^ swzb) * 8);
#pragma unroll
            for (int mt = 0; mt < 2; mt++) {
                f32x4 sc[2];
#pragma unroll
                for (int nt = 0; nt < 2; nt++) {
                    f32x4 z = ZERO4;
                    sc[nt] = MFMA_BF16(ka[0][mt], qb[nt][0], z);
                    sc[nt] = MFMA_BF16(ka[1][mt], qb[nt][1], sc[nt]);
                }
#pragma unroll
                for (int nt = 0; nt < 2; nt++) {
                    float p0 = fast_exp2(sc[nt][0]);
                    float p1 = fast_exp2(sc[nt][1]);
                    float p2 = fast_exp2(sc[nt][2]);
                    float p3 = fast_exp2(sc[nt][3]);
                    lp[nt] += (p0 + p1) + (p2 + p3);
                    u32x2 pk;
                    pk[0] = pack_bf16(p0, p1);
                    pk[1] = pack_bf16(p2, p3);
                    // row = nt*16+lr (stride 32); chunk (2*mt + quad/2) ^ swz3; 8B half = quad&1
                    *(u32x2*)(Pw + (nt * 16 + lr) * 32 + ((2 * mt + (quad >> 1)) ^ swz3) * 8 +
                              (quad & 1) * 4) = pk;
                }
            }

            // ---- PV half: k-dim = 32 t's of this half ----
            bf16x8 vb[4];
#pragma unroll
            for (int et = 0; et < 4; et++)
                vb[et] = ldfrag(cV + (et * 16 + lr) * 64 + ((half * 4 + quad) ^ swzb) * 8);
            bf16x8 pa[2];
#pragma unroll
            for (int g = 0; g < 2; g++)
                pa[g] = ldfrag(Pw + (g * 16 + lr) * 32 + (quad ^ swz3) * 8);
#pragma unroll
            for (int g = 0; g < 2; g++) {
                o[g][0] = MFMA_BF16(pa[g], vb[0], o[g][0]);
                o[g][1] = MFMA_BF16(pa[g], vb[1], o[g][1]);
                o[g][2] = MFMA_BF16(pa[g], vb[2], o[g][2]);
                o[g][3] = MFMA_BF16(pa[g], vb[3], o[g][3]);
            }
        }
    }

    // final denominator: reduce across the 4 quads
#pragma unroll
    for (int g = 0; g < 2; g++) {
        float l = lp[g];
        l += __shfl_xor(l, 16, 64);
        l += __shfl_xor(l, 32, 64);
        lp[g] = l;
    }

    // normalize + write attn [B,S,H*E] bf16
    const int h = bh & 15, b = bh >> 4;
#pragma unroll
    for (int g = 0; g < 2; g++) {
#pragma unroll
        for (int r = 0; r < 4; r++) {
            float l = __shfl(lp[g], quad * 4 + r, 16);
            float inv = 1.0f / l;
            int s = q0 + w * 32 + g * 16 + quad * 4 + r;
#pragma unroll
            for (int et = 0; et < 4; et++) {
                int col = h * 64 + et * 16 + lr;
                Out[((size_t)(b * 2048 + s)) * 1024 + col] = f2bf(o[g][et][r] * inv);
            }
        }
    }
}

// ---------------- launch ----------------

extern "C" void kernel_launch(void* const* d_in, const int* in_sizes, int n_in,
                              void* d_out, int out_size, void* d_ws, size_t ws_size,
                              hipStream_t stream) {
    const float* x  = (const float*)d_in[0];
    const float* Wq = (const float*)d_in[1];
    const float* bq = (const float*)d_in[2];
    const float* Wk = (const float*)d_in[3];
    const float* bk = (const float*)d_in[4];
    const float* Wv = (const float*)d_in[5];
    const float* bv = (const float*)d_in[6];
    const float* Wo = (const float*)d_in[7];
    const float* bo = (const float*)d_in[8];
    float* out = (float*)d_out;

    char* ws = (char*)d_ws;
    unsigned short* xb    = (unsigned short*)(ws);              // 16 MiB; reused as attn buffer
    unsigned short* WqkvT = (unsigned short*)(ws + 16777216);   // 6 MiB
    unsigned short* WoT   = (unsigned short*)(ws + 23068672);   // 2 MiB
    unsigned short* Qb    = (unsigned short*)(ws + 25165824);   // 16 MiB
    unsigned short* Kb    = (unsigned short*)(ws + 41943040);   // 16 MiB
    unsigned short* VTb   = (unsigned short*)(ws + 58720256);   // 16 MiB (total 72 MiB)
    unsigned short* attn  = xb;  // xb is dead after gemm_qkv

    cvt_x_kernel<<<dim3(4096), dim3(256), 0, stream>>>(x, xb);
    cvt_wqkvT_kernel<<<dim3(12, 128), dim3(256), 0, stream>>>(Wq, Wk, Wv, WqkvT);
    cvt_woT_kernel<<<dim3(4, 128), dim3(256), 0, stream>>>(Wo, WoT);
    gemm_qkv_kernel<<<dim3(24, 64), dim3(256), 0, stream>>>(xb, WqkvT, bq, bk, bv, Qb, Kb, VTb);
    attn_fa_kernel<<<dim3(64, 16), dim3(256), 0, stream>>>(Qb, Kb, VTb, attn);
    gemm_out_kernel<<<dim3(8, 64), dim3(256), 0, stream>>>(attn, WoT, bo, out);
}

// Round 7
// 291.475 us; speedup vs baseline: 1.0550x; 1.0265x over previous
//
#include <hip/hip_runtime.h>

typedef __bf16 bf16x8 __attribute__((ext_vector_type(8)));
typedef float f32x4 __attribute__((ext_vector_type(4)));
typedef unsigned int u32x4 __attribute__((ext_vector_type(4)));
typedef unsigned int u32x2 __attribute__((ext_vector_type(2)));
typedef unsigned short u16x8 __attribute__((ext_vector_type(8)));

#define MFMA_BF16(a, b, c) __builtin_amdgcn_mfma_f32_16x16x32_bf16((a), (b), (c), 0, 0, 0)

// 0.125 (1/sqrt(64)) * log2(e): folded into Q so softmax uses raw exp2
#define QSCALE 0.18033688011112043f

__device__ __forceinline__ unsigned short f2bf(float f) {
    unsigned int u = __builtin_bit_cast(unsigned int, f);
    u += 0x7FFFu + ((u >> 16) & 1u);
    return (unsigned short)(u >> 16);
}

// manual RNE pack (bit-identical to f2bf pairs) — numerically sensitive V/Q paths stay RNE.
__device__ __forceinline__ unsigned int pack_bf16_rne(float a, float b) {
    unsigned int ua = __builtin_bit_cast(unsigned int, a);
    unsigned int ub = __builtin_bit_cast(unsigned int, b);
    ua += 0x7FFFu + ((ua >> 16) & 1u);
    ub += 0x7FFFu + ((ub >> 16) & 1u);
    return __builtin_amdgcn_perm(ub, ua, 0x07060302);
}

// cheap pack for P (values in [0,1], self-normalizing) — validated earlier
#if __has_builtin(__builtin_amdgcn_cvt_pk_bf16_f32)
typedef __bf16 bf16x2 __attribute__((ext_vector_type(2)));
__device__ __forceinline__ unsigned int pack_bf16(float a, float b) {
    return __builtin_bit_cast(unsigned int, __builtin_amdgcn_cvt_pk_bf16_f32(a, b));
}
#else
__device__ __forceinline__ unsigned int pack_bf16(float a, float b) {
    return pack_bf16_rne(a, b);
}
#endif

#if __has_builtin(__builtin_amdgcn_exp2f)
__device__ __forceinline__ float fast_exp2(float x) { return __builtin_amdgcn_exp2f(x); }
#else
__device__ __forceinline__ float fast_exp2(float x) { return exp2f(x); }
#endif

__device__ __forceinline__ bf16x8 ldfrag(const unsigned short* p) {
    return __builtin_bit_cast(bf16x8, *(const u32x4*)p);
}

// async global->LDS, 16B per lane; LDS dst = wave-uniform base + lane*16B
typedef const __attribute__((address_space(1))) void* gas_t;
typedef __attribute__((address_space(3))) void* las_t;
__device__ __forceinline__ void dma16(const unsigned short* g, unsigned short* l) {
    __builtin_amdgcn_global_load_lds((gas_t)(const void*)g, (las_t)(void*)l, 16, 0, 0);
}

// drain this wave's outstanding DMA/LDS ops, then block barrier.
__device__ __forceinline__ void pipeline_barrier() {
    __builtin_amdgcn_s_waitcnt(0);
    __syncthreads();
}

// ---------------- conversion kernels ----------------

__global__ void cvt_x_kernel(const float* __restrict__ in, unsigned short* __restrict__ out) {
    long long t = (long long)blockIdx.x * 256 + threadIdx.x;
    const f32x4* p = (const f32x4*)in + t * 2;
    f32x4 v0 = p[0], v1 = p[1];
    u16x8 o;
    o[0] = f2bf(v0[0]); o[1] = f2bf(v0[1]); o[2] = f2bf(v0[2]); o[3] = f2bf(v0[3]);
    o[4] = f2bf(v1[0]); o[5] = f2bf(v1[1]); o[6] = f2bf(v1[2]); o[7] = f2bf(v1[3]);
    *((u16x8*)out + t) = o;
}

__global__ void cvt_wqkvT_kernel(const float* __restrict__ Wq, const float* __restrict__ Wk,
                                 const float* __restrict__ Wv, unsigned short* __restrict__ WT) {
    int n = blockIdx.x * 256 + threadIdx.x;
    int d0 = blockIdx.y * 8;
    int proj = n >> 10, rem = n & 1023, h = rem >> 6, e = rem & 63;
    const float* W = (proj == 0) ? Wq : (proj == 1) ? Wk : Wv;
    const float* src = W + (size_t)h * 65536 + (size_t)d0 * 64 + e;
    u16x8 o;
#pragma unroll
    for (int j = 0; j < 8; j++) o[j] = f2bf(src[j * 64]);
    *(u16x8*)(WT + (size_t)n * 1024 + d0) = o;
}

__global__ void cvt_woT_kernel(const float* __restrict__ Wo, unsigned short* __restrict__ WoT) {
    int n = blockIdx.x * 256 + threadIdx.x;
    int d0 = blockIdx.y * 8;
    const float* src = Wo + (size_t)d0 * 1024 + n;
    u16x8 o;
#pragma unroll
    for (int j = 0; j < 8; j++) o[j] = f2bf(src[j * 1024]);
    *(u16x8*)(WoT + (size_t)n * 1024 + d0) = o;
}

// ---------------- GEMM kernels: single-barrier double-buffered DMA pipeline ----------------
// LDS: [2][128][32] u16 per operand; LDS(r,c-chunk) = global(r, c ^ (r&3)); frag chunk = quad ^ (lr&3).
// R10: epilogue attack. Q now stored TRANSPOSED [bh][e][s] so its epilogue uses the
// validated V-style packed b64-down-s stores (coalesced 8B) instead of 64 scalar 2B
// stores/thread. K keeps [bh][s][e] (attn DMA needs row-major t). gemm_out transposes
// its 64x16 f32 slabs through LDS (reusing As post-loop) to emit dwordx4 stores.

__global__ __launch_bounds__(256) void gemm_qkv_kernel(
    const unsigned short* __restrict__ A, const unsigned short* __restrict__ BT,
    const float* __restrict__ bq, const float* __restrict__ bk, const float* __restrict__ bv,
    unsigned short* __restrict__ QTo, unsigned short* __restrict__ Ko, unsigned short* __restrict__ VTo) {
    __shared__ unsigned short As[2 * 128 * 32];
    __shared__ unsigned short Bs[2 * 128 * 32];
    const int tid = threadIdx.x;
    const int m0 = blockIdx.y * 128, n0 = blockIdx.x * 128;
    const int w = tid >> 6, lane = tid & 63, lr = lane & 15, quad = lane >> 4;
    const int wy = w >> 1, wx = w & 1;
    f32x4 acc[4][4];
#pragma unroll
    for (int i = 0; i < 4; i++)
#pragma unroll
        for (int j = 0; j < 4; j++) acc[i][j] = (f32x4){0.f, 0.f, 0.f, 0.f};
    const int drow = lane >> 2;
    const int dchunk = (lane & 3) ^ (drow & 3);
    const unsigned short* gA = A + (size_t)(m0 + w * 32 + drow) * 1024 + dchunk * 8;
    const unsigned short* gB = BT + (size_t)(n0 + w * 32 + drow) * 1024 + dchunk * 8;
    const int swav = (w * 32) * 32;
    const int fcol = (quad ^ (lr & 3)) * 8;
    // prologue: tile 0 -> buf 0
    dma16(gA, As + swav);
    dma16(gA + 16 * 1024, As + swav + 16 * 32);
    dma16(gB, Bs + swav);
    dma16(gB + 16 * 1024, Bs + swav + 16 * 32);
    for (int k0 = 0; k0 < 1024; k0 += 32) {
        const int cur = (k0 >> 5) & 1;
        const unsigned short* cA = As + cur * 4096;
        const unsigned short* cB = Bs + cur * 4096;
        pipeline_barrier();  // drains this wave's DMA for tile k0; releases buf[cur^1]
        bf16x8 af[4], bfr[4];
#pragma unroll
        for (int i = 0; i < 4; i++) af[i] = ldfrag(cA + (wy * 64 + i * 16 + lr) * 32 + fcol);
#pragma unroll
        for (int j = 0; j < 4; j++) bfr[j] = ldfrag(cB + (wx * 64 + j * 16 + lr) * 32 + fcol);
        if (k0 + 32 < 1024) {  // prefetch tile k0+32 into other buffer
            const int nb = (cur ^ 1) * 4096 + swav;
            dma16(gA + k0 + 32, As + nb);
            dma16(gA + k0 + 32 + 16 * 1024, As + nb + 16 * 32);
            dma16(gB + k0 + 32, Bs + nb);
            dma16(gB + k0 + 32 + 16 * 1024, Bs + nb + 16 * 32);
        }
#pragma unroll
        for (int i = 0; i < 4; i++)
#pragma unroll
            for (int j = 0; j < 4; j++) acc[i][j] = MFMA_BF16(af[i], bfr[j], acc[i][j]);
    }
#pragma unroll
    for (int j = 0; j < 4; j++) {
        int n = n0 + wx * 64 + j * 16 + lr;
        int proj = n >> 10, rem = n & 1023, h = rem >> 6, e = rem & 63;
        if (proj == 0) {
            // Q: transposed [bh, e, s], packed b64 stores down s (RNE; QSCALE folded)
            float bb = bq[rem];
#pragma unroll
            for (int i = 0; i < 4; i++) {
                int m = m0 + wy * 64 + i * 16 + quad * 4;
                int batch = m >> 11, s = m & 2047;
                u32x2 pk;
                pk[0] = pack_bf16_rne((acc[i][j][0] + bb) * QSCALE, (acc[i][j][1] + bb) * QSCALE);
                pk[1] = pack_bf16_rne((acc[i][j][2] + bb) * QSCALE, (acc[i][j][3] + bb) * QSCALE);
                *(u32x2*)(QTo + (((size_t)batch * 16 + h) * 64 + e) * 2048 + s) = pk;
            }
        } else if (proj == 2) {
            // V: write transposed [bh, e, s] with packed b64 stores down s (RNE pack!)
            float bb = bv[rem];
#pragma unroll
            for (int i = 0; i < 4; i++) {
                int m = m0 + wy * 64 + i * 16 + quad * 4;
                int batch = m >> 11, s = m & 2047;
                u32x2 pk;
                pk[0] = pack_bf16_rne(acc[i][j][0] + bb, acc[i][j][1] + bb);
                pk[1] = pack_bf16_rne(acc[i][j][2] + bb, acc[i][j][3] + bb);
                *(u32x2*)(VTo + (((size_t)batch * 16 + h) * 64 + e) * 2048 + s) = pk;
            }
        } else {
            // K: [bh, s, e] (attn DMA needs row-major t) — scalar stores
            float bb = bk[rem];
#pragma unroll
            for (int i = 0; i < 4; i++) {
#pragma unroll
                for (int r = 0; r < 4; r++) {
                    int m = m0 + wy * 64 + i * 16 + quad * 4 + r;
                    int batch = m >> 11, s = m & 2047;
                    Ko[(((size_t)batch * 16 + h) * 2048 + s) * 64 + e] = f2bf(acc[i][j][r] + bb);
                }
            }
        }
    }
}

__global__ __launch_bounds__(256) void gemm_out_kernel(
    const unsigned short* __restrict__ A, const unsigned short* __restrict__ BT,
    const float* __restrict__ bo, float* __restrict__ out) {
    __shared__ unsigned short As[2 * 128 * 32];
    __shared__ unsigned short Bs[2 * 128 * 32];
    const int tid = threadIdx.x;
    const int m0 = blockIdx.y * 128, n0 = blockIdx.x * 128;
    const int w = tid >> 6, lane = tid & 63, lr = lane & 15, quad = lane >> 4;
    const int wy = w >> 1, wx = w & 1;
    f32x4 acc[4][4];
#pragma unroll
    for (int i = 0; i < 4; i++)
#pragma unroll
        for (int j = 0; j < 4; j++) acc[i][j] = (f32x4){0.f, 0.f, 0.f, 0.f};
    const int drow = lane >> 2;
    const int dchunk = (lane & 3) ^ (drow & 3);
    const unsigned short* gA = A + (size_t)(m0 + w * 32 + drow) * 1024 + dchunk * 8;
    const unsigned short* gB = BT + (size_t)(n0 + w * 32 + drow) * 1024 + dchunk * 8;
    const int swav = (w * 32) * 32;
    const int fcol = (quad ^ (lr & 3)) * 8;
    dma16(gA, As + swav);
    dma16(gA + 16 * 1024, As + swav + 16 * 32);
    dma16(gB, Bs + swav);
    dma16(gB + 16 * 1024, Bs + swav + 16 * 32);
    for (int k0 = 0; k0 < 1024; k0 += 32) {
        const int cur = (k0 >> 5) & 1;
        const unsigned short* cA = As + cur * 4096;
        const unsigned short* cB = Bs + cur * 4096;
        pipeline_barrier();
        bf16x8 af[4], bfr[4];
#pragma unroll
        for (int i = 0; i < 4; i++) af[i] = ldfrag(cA + (wy * 64 + i * 16 + lr) * 32 + fcol);
#pragma unroll
        for (int j = 0; j < 4; j++) bfr[j] = ldfrag(cB + (wx * 64 + j * 16 + lr) * 32 + fcol);
        if (k0 + 32 < 1024) {
            const int nb = (cur ^ 1) * 4096 + swav;
            dma16(gA + k0 + 32, As + nb);
            dma16(gA + k0 + 32 + 16 * 1024, As + nb + 16 * 32);
            dma16(gB + k0 + 32, Bs + nb);
            dma16(gB + k0 + 32 + 16 * 1024, Bs + nb + 16 * 32);
        }
#pragma unroll
        for (int i = 0; i < 4; i++)
#pragma unroll
            for (int j = 0; j < 4; j++) acc[i][j] = MFMA_BF16(af[i], bfr[j], acc[i][j]);
    }
    // R10 epilogue: transpose each wave's 64x16 f32 slab through LDS (As reused,
    // wave-private 4 KiB) -> coalesced dwordx4 stores (16 instrs vs 64 scalar dwords).
    __syncthreads();  // all waves done reading K-loop fragments; As is free
    float* ws4 = (float*)As + w * 1024;  // 64 rows x 16 cols f32
#pragma unroll
    for (int j = 0; j < 4; j++) {
        int n = n0 + wx * 64 + j * 16 + lr;
        float bb = bo[n];
#pragma unroll
        for (int i = 0; i < 4; i++)
#pragma unroll
            for (int r = 0; r < 4; r++)
                ws4[(i * 16 + quad * 4 + r) * 16 + lr] = acc[i][j][r] + bb;
        // same-wave DS in-order + compiler alias analysis give write->read ordering
#pragma unroll
        for (int t = 0; t < 4; t++) {
            f32x4 v = *(f32x4*)(ws4 + (t * 16 + (lane >> 2)) * 16 + (lane & 3) * 4);
            int m = m0 + wy * 64 + t * 16 + (lane >> 2);
            *(f32x4*)(out + (size_t)m * 1024 + n0 + wx * 64 + j * 16 + (lane & 3) * 4) = v;
        }
    }
}

// ---------------- flash attention (S^T = K Q^T, no-max softmax, dbuf DMA pipeline) ----------------
// R10: EXACT R2 structure (measured 94.9 µs) — the only edit is the Q-fragment load,
// which now reads the transposed Q [bh][e][s] via 128 one-time scalar loads (amortized
// over 32 tiles; enables the coalesced Q epilogue in gemm_qkv).
// P buffer: wave-private 64x64 u16, 16B-chunk XOR swizzle (chunk ^ (row&7)).
// K/V tiles: [2][64][64] u16, source-swizzled: LDS(r,c) = global(r, c ^ (r&7));
// frag reads use chunk (kc*4+quad) ^ (lr&7) -> <=2-way (free) b128.
__global__ __launch_bounds__(256, 2) void attn_fa_kernel(
    const unsigned short* __restrict__ QT, const unsigned short* __restrict__ K,
    const unsigned short* __restrict__ VT, unsigned short* __restrict__ Out) {
    __shared__ unsigned short Ks[2 * 64 * 64];
    __shared__ unsigned short Vs[2 * 64 * 64];
    __shared__ unsigned short Ps[256 * 64];  // wave-private 64-row P regions, XOR-swizzled
    const int bh = blockIdx.x;               // bh on x: all 8 q-blocks of a head share an XCD (id%8)
    const int q0 = blockIdx.y * 256;
    const int tid = threadIdx.x;
    const int w = tid >> 6, lane = tid & 63, lr = lane & 15, quad = lane >> 4;
    const unsigned short* Qh = QT + (size_t)bh * 64 * 2048;  // [e][s]
    const unsigned short* Kh = K + (size_t)bh * 2048 * 64;
    const unsigned short* Vh = VT + (size_t)bh * 64 * 2048;

    const f32x4 ZERO4 = {0.f, 0.f, 0.f, 0.f};

    // DMA setup: wave w covers K/V rows w*16 .. w*16+15 (2 instrs of 8 rows each)
    const int drow = lane >> 3;
    const int dchunk = (lane & 7) ^ drow;
    const unsigned short* gK = Kh + (size_t)(w * 16 + drow) * 64 + dchunk * 8;
    const unsigned short* gV = Vh + (size_t)(w * 16 + drow) * 2048 + dchunk * 8;
    const int swav = (w * 16) * 64;
    // prologue: tile 0 -> buf 0
    dma16(gK, Ks + swav);
    dma16(gK + 8 * 64, Ks + swav + 8 * 64);
    dma16(gV, Vs + swav);
    dma16(gV + 8 * 2048, Vs + swav + 8 * 64);

    // Q fragments from transposed Q (one-time scalar gather; stays in regs)
    bf16x8 qb[4][2];  // [q-16-group][kc]
#pragma unroll
    for (int nt = 0; nt < 4; nt++)
#pragma unroll
        for (int kc = 0; kc < 2; kc++) {
            u16x8 t8;
#pragma unroll
            for (int jj = 0; jj < 8; jj++)
                t8[jj] = Qh[(size_t)(kc * 32 + quad * 8 + jj) * 2048 + q0 + w * 64 + nt * 16 + lr];
            qb[nt][kc] = __builtin_bit_cast(bf16x8, t8);
        }

    f32x4 o[4][4];
#pragma unroll
    for (int i = 0; i < 4; i++)
#pragma unroll
        for (int j = 0; j < 4; j++) o[i][j] = ZERO4;
    float lp[4] = {0.f, 0.f, 0.f, 0.f};

    unsigned short* const Pw = Ps + (w * 64) * 64;  // this wave's private P rows
    const int swzb = lr & 7;                        // row&7 for all P rows this lane touches

    for (int t0 = 0; t0 < 2048; t0 += 64) {
        const int cur = (t0 >> 6) & 1;
        const unsigned short* cK = Ks + cur * 4096;
        const unsigned short* cV = Vs + cur * 4096;
        pipeline_barrier();  // drains this tile's DMA; releases other buffer
        // hoist ALL K/V fragment reads before the prefetch DMA issue
        bf16x8 ka[2][4], vb[2][4];
#pragma unroll
        for (int kc = 0; kc < 2; kc++)
#pragma unroll
            for (int mt = 0; mt < 4; mt++) {
                int fc = ((kc * 4 + quad) ^ swzb) * 8;
                ka[kc][mt] = ldfrag(cK + (mt * 16 + lr) * 64 + fc);
                vb[kc][mt] = ldfrag(cV + (mt * 16 + lr) * 64 + fc);
            }
        if (t0 + 64 < 2048) {  // prefetch next tile into other buffer
            const int nb = (cur ^ 1) * 4096 + swav;
            dma16(gK + (size_t)(t0 + 64) * 64, Ks + nb);
            dma16(gK + (size_t)(t0 + 64) * 64 + 8 * 64, Ks + nb + 8 * 64);
            dma16(gV + t0 + 64, Vs + nb);
            dma16(gV + t0 + 64 + 8 * 2048, Vs + nb + 8 * 64);
        }

        // S^T = K·Q^T, per-mt (16 t-rows): MFMA pair -> exp2 -> pack -> P write.
#pragma unroll
        for (int mt = 0; mt < 4; mt++) {
            f32x4 sc[4];
#pragma unroll
            for (int nt = 0; nt < 4; nt++) {
                f32x4 z = ZERO4;
                sc[nt] = MFMA_BF16(ka[0][mt], qb[nt][0], z);
                sc[nt] = MFMA_BF16(ka[1][mt], qb[nt][1], sc[nt]);
            }
#pragma unroll
            for (int nt = 0; nt < 4; nt++) {
                float p0 = fast_exp2(sc[nt][0]);
                float p1 = fast_exp2(sc[nt][1]);
                float p2 = fast_exp2(sc[nt][2]);
                float p3 = fast_exp2(sc[nt][3]);
                lp[nt] += (p0 + p1) + (p2 + p3);
                u32x2 pk;
                pk[0] = pack_bf16(p0, p1);
                pk[1] = pack_bf16(p2, p3);
                // row = nt*16+lr; 16B chunk (2*mt + quad/2) swizzled by row&7; 8B half = quad&1
                *(u32x2*)(Pw + (nt * 16 + lr) * 64 + ((2 * mt + (quad >> 1)) ^ swzb) * 8 +
                          (quad & 1) * 4) = pk;
            }
        }

        // O += P·V  (A = own-wave P rows — wave-private region, lgkm-ordered)
#pragma unroll
        for (int kc = 0; kc < 2; kc++) {
            const int fc = ((kc * 4 + quad) ^ swzb) * 8;
#pragma unroll
            for (int g = 0; g < 4; g++) {
                bf16x8 pa = ldfrag(Pw + (g * 16 + lr) * 64 + fc);
                o[g][0] = MFMA_BF16(pa, vb[kc][0], o[g][0]);
                o[g][1] = MFMA_BF16(pa, vb[kc][1], o[g][1]);
                o[g][2] = MFMA_BF16(pa, vb[kc][2], o[g][2]);
                o[g][3] = MFMA_BF16(pa, vb[kc][3], o[g][3]);
            }
        }
    }

    // final denominator: reduce across the 4 quads
#pragma unroll
    for (int g = 0; g < 4; g++) {
        float l = lp[g];
        l += __shfl_xor(l, 16, 64);
        l += __shfl_xor(l, 32, 64);
        lp[g] = l;
    }

    // normalize + write attn [B,S,H*E] bf16
    const int h = bh & 15, b = bh >> 4;
#pragma unroll
    for (int g = 0; g < 4; g++) {
#pragma unroll
        for (int r = 0; r < 4; r++) {
            float l = __shfl(lp[g], quad * 4 + r, 16);
            float inv = 1.0f / l;
            int s = q0 + w * 64 + g * 16 + quad * 4 + r;
#pragma unroll
            for (int et = 0; et < 4; et++) {
                int col = h * 64 + et * 16 + lr;
                Out[((size_t)(b * 2048 + s)) * 1024 + col] = f2bf(o[g][et][r] * inv);
            }
        }
    }
}

// ---------------- launch ----------------

extern "C" void kernel_launch(void* const* d_in, const int* in_sizes, int n_in,
                              void* d_out, int out_size, void* d_ws, size_t ws_size,
                              hipStream_t stream) {
    const float* x  = (const float*)d_in[0];
    const float* Wq = (const float*)d_in[1];
    const float* bq = (const float*)d_in[2];
    const float* Wk = (const float*)d_in[3];
    const float* bk = (const float*)d_in[4];
    const float* Wv = (const float*)d_in[5];
    const float* bv = (const float*)d_in[6];
    const float* Wo = (const float*)d_in[7];
    const float* bo = (const float*)d_in[8];
    float* out = (float*)d_out;

    char* ws = (char*)d_ws;
    unsigned short* xb    = (unsigned short*)(ws);              // 16 MiB; reused as attn buffer
    unsigned short* WqkvT = (unsigned short*)(ws + 16777216);   // 6 MiB
    unsigned short* WoT   = (unsigned short*)(ws + 23068672);   // 2 MiB
    unsigned short* QTb   = (unsigned short*)(ws + 25165824);   // 16 MiB (transposed [bh][e][s])
    unsigned short* Kb    = (unsigned short*)(ws + 41943040);   // 16 MiB
    unsigned short* VTb   = (unsigned short*)(ws + 58720256);   // 16 MiB (total 72 MiB)
    unsigned short* attn  = xb;  // xb is dead after gemm_qkv

    cvt_x_kernel<<<dim3(4096), dim3(256), 0, stream>>>(x, xb);
    cvt_wqkvT_kernel<<<dim3(12, 128), dim3(256), 0, stream>>>(Wq, Wk, Wv, WqkvT);
    cvt_woT_kernel<<<dim3(4, 128), dim3(256), 0, stream>>>(Wo, WoT);
    gemm_qkv_kernel<<<dim3(24, 64), dim3(256), 0, stream>>>(xb, WqkvT, bq, bk, bv, QTb, Kb, VTb);
    attn_fa_kernel<<<dim3(64, 8), dim3(256), 0, stream>>>(QTb, Kb, VTb, attn);
    gemm_out_kernel<<<dim3(8, 64), dim3(256), 0, stream>>>(attn, WoT, bo, out);
}

// Round 8
// 279.052 us; speedup vs baseline: 1.1020x; 1.0445x over previous
//
#include <hip/hip_runtime.h>

typedef __bf16 bf16x8 __attribute__((ext_vector_type(8)));
typedef float f32x4 __attribute__((ext_vector_type(4)));
typedef unsigned int u32x4 __attribute__((ext_vector_type(4)));
typedef unsigned int u32x2 __attribute__((ext_vector_type(2)));
typedef unsigned short u16x8 __attribute__((ext_vector_type(8)));

#define MFMA_BF16(a, b, c) __builtin_amdgcn_mfma_f32_16x16x32_bf16((a), (b), (c), 0, 0, 0)

// 0.125 (1/sqrt(64)) * log2(e): folded into Q so softmax uses raw exp2
#define QSCALE 0.18033688011112043f

__device__ __forceinline__ unsigned short f2bf(float f) {
    unsigned int u = __builtin_bit_cast(unsigned int, f);
    u += 0x7FFFu + ((u >> 16) & 1u);
    return (unsigned short)(u >> 16);
}

// manual RNE pack (bit-identical to f2bf pairs) — numerically sensitive V path stays RNE.
__device__ __forceinline__ unsigned int pack_bf16_rne(float a, float b) {
    unsigned int ua = __builtin_bit_cast(unsigned int, a);
    unsigned int ub = __builtin_bit_cast(unsigned int, b);
    ua += 0x7FFFu + ((ua >> 16) & 1u);
    ub += 0x7FFFu + ((ub >> 16) & 1u);
    return __builtin_amdgcn_perm(ub, ua, 0x07060302);
}

// cheap pack for P (values in [0,1], self-normalizing) — validated earlier
#if __has_builtin(__builtin_amdgcn_cvt_pk_bf16_f32)
typedef __bf16 bf16x2 __attribute__((ext_vector_type(2)));
__device__ __forceinline__ unsigned int pack_bf16(float a, float b) {
    return __builtin_bit_cast(unsigned int, __builtin_amdgcn_cvt_pk_bf16_f32(a, b));
}
#else
__device__ __forceinline__ unsigned int pack_bf16(float a, float b) {
    return pack_bf16_rne(a, b);
}
#endif

#if __has_builtin(__builtin_amdgcn_exp2f)
__device__ __forceinline__ float fast_exp2(float x) { return __builtin_amdgcn_exp2f(x); }
#else
__device__ __forceinline__ float fast_exp2(float x) { return exp2f(x); }
#endif

__device__ __forceinline__ bf16x8 ldfrag(const unsigned short* p) {
    return __builtin_bit_cast(bf16x8, *(const u32x4*)p);
}

// async global->LDS, 16B per lane; LDS dst = wave-uniform base + lane*16B
typedef const __attribute__((address_space(1))) void* gas_t;
typedef __attribute__((address_space(3))) void* las_t;
__device__ __forceinline__ void dma16(const unsigned short* g, unsigned short* l) {
    __builtin_amdgcn_global_load_lds((gas_t)(const void*)g, (las_t)(void*)l, 16, 0, 0);
}

// drain this wave's outstanding DMA/LDS ops, then block barrier.
__device__ __forceinline__ void pipeline_barrier() {
    __builtin_amdgcn_s_waitcnt(0);
    __syncthreads();
}

// ---------------- fused conversion kernel (R11: 3 launches -> 1) ----------------
// blocks [0,4096): x -> bf16.  [4096,5632): Wq/Wk/Wv transpose+cvt.  [5632,6144): Wo^T cvt.
// All branches wave-uniform (blockIdx-based). Per-branch code identical to the R2 kernels.

__global__ void cvt_fused_kernel(const float* __restrict__ x,
                                 const float* __restrict__ Wq, const float* __restrict__ Wk,
                                 const float* __restrict__ Wv, const float* __restrict__ Wo,
                                 unsigned short* __restrict__ xb, unsigned short* __restrict__ WT,
                                 unsigned short* __restrict__ WoT) {
    const int b = blockIdx.x;
    const int tid = threadIdx.x;
    if (b < 4096) {
        long long t = (long long)b * 256 + tid;
        const f32x4* p = (const f32x4*)x + t * 2;
        f32x4 v0 = p[0], v1 = p[1];
        u16x8 o;
        o[0] = f2bf(v0[0]); o[1] = f2bf(v0[1]); o[2] = f2bf(v0[2]); o[3] = f2bf(v0[3]);
        o[4] = f2bf(v1[0]); o[5] = f2bf(v1[1]); o[6] = f2bf(v1[2]); o[7] = f2bf(v1[3]);
        *((u16x8*)xb + t) = o;
    } else if (b < 5632) {
        int bb = b - 4096;
        int bx = bb % 12, by = bb / 12;
        int n = bx * 256 + tid;
        int d0 = by * 8;
        int proj = n >> 10, rem = n & 1023, h = rem >> 6, e = rem & 63;
        const float* W = (proj == 0) ? Wq : (proj == 1) ? Wk : Wv;
        const float* src = W + (size_t)h * 65536 + (size_t)d0 * 64 + e;
        u16x8 o;
#pragma unroll
        for (int j = 0; j < 8; j++) o[j] = f2bf(src[j * 64]);
        *(u16x8*)(WT + (size_t)n * 1024 + d0) = o;
    } else {
        int bb = b - 5632;
        int bx = bb % 4, by = bb / 4;
        int n = bx * 256 + tid;
        int d0 = by * 8;
        const float* src = Wo + (size_t)d0 * 1024 + n;
        u16x8 o;
#pragma unroll
        for (int j = 0; j < 8; j++) o[j] = f2bf(src[j * 1024]);
        *(u16x8*)(WoT + (size_t)n * 1024 + d0) = o;
    }
}

// ---------------- GEMM kernels: single-barrier double-buffered DMA pipeline ----------------
// EXACT R2 form (281.8 µs champion). LDS: [2][128][32] u16 per operand;
// LDS(r,c-chunk) = global(r, c ^ (r&3)); frag chunk = quad ^ (lr&3).

__global__ __launch_bounds__(256) void gemm_qkv_kernel(
    const unsigned short* __restrict__ A, const unsigned short* __restrict__ BT,
    const float* __restrict__ bq, const float* __restrict__ bk, const float* __restrict__ bv,
    unsigned short* __restrict__ Qo, unsigned short* __restrict__ Ko, unsigned short* __restrict__ VTo) {
    __shared__ unsigned short As[2 * 128 * 32];
    __shared__ unsigned short Bs[2 * 128 * 32];
    const int tid = threadIdx.x;
    const int m0 = blockIdx.y * 128, n0 = blockIdx.x * 128;
    const int w = tid >> 6, lane = tid & 63, lr = lane & 15, quad = lane >> 4;
    const int wy = w >> 1, wx = w & 1;
    f32x4 acc[4][4];
#pragma unroll
    for (int i = 0; i < 4; i++)
#pragma unroll
        for (int j = 0; j < 4; j++) acc[i][j] = (f32x4){0.f, 0.f, 0.f, 0.f};
    const int drow = lane >> 2;
    const int dchunk = (lane & 3) ^ (drow & 3);
    const unsigned short* gA = A + (size_t)(m0 + w * 32 + drow) * 1024 + dchunk * 8;
    const unsigned short* gB = BT + (size_t)(n0 + w * 32 + drow) * 1024 + dchunk * 8;
    const int swav = (w * 32) * 32;
    const int fcol = (quad ^ (lr & 3)) * 8;
    // prologue: tile 0 -> buf 0
    dma16(gA, As + swav);
    dma16(gA + 16 * 1024, As + swav + 16 * 32);
    dma16(gB, Bs + swav);
    dma16(gB + 16 * 1024, Bs + swav + 16 * 32);
    for (int k0 = 0; k0 < 1024; k0 += 32) {
        const int cur = (k0 >> 5) & 1;
        const unsigned short* cA = As + cur * 4096;
        const unsigned short* cB = Bs + cur * 4096;
        pipeline_barrier();  // drains this wave's DMA for tile k0; releases buf[cur^1]
        bf16x8 af[4], bfr[4];
#pragma unroll
        for (int i = 0; i < 4; i++) af[i] = ldfrag(cA + (wy * 64 + i * 16 + lr) * 32 + fcol);
#pragma unroll
        for (int j = 0; j < 4; j++) bfr[j] = ldfrag(cB + (wx * 64 + j * 16 + lr) * 32 + fcol);
        if (k0 + 32 < 1024) {  // prefetch tile k0+32 into other buffer
            const int nb = (cur ^ 1) * 4096 + swav;
            dma16(gA + k0 + 32, As + nb);
            dma16(gA + k0 + 32 + 16 * 1024, As + nb + 16 * 32);
            dma16(gB + k0 + 32, Bs + nb);
            dma16(gB + k0 + 32 + 16 * 1024, Bs + nb + 16 * 32);
        }
#pragma unroll
        for (int i = 0; i < 4; i++)
#pragma unroll
            for (int j = 0; j < 4; j++) acc[i][j] = MFMA_BF16(af[i], bfr[j], acc[i][j]);
    }
#pragma unroll
    for (int j = 0; j < 4; j++) {
        int n = n0 + wx * 64 + j * 16 + lr;
        int proj = n >> 10, rem = n & 1023, h = rem >> 6, e = rem & 63;
        if (proj == 2) {
            // V: write transposed [bh, e, s] with packed b64 stores down s (RNE pack!)
            float bb = bv[rem];
#pragma unroll
            for (int i = 0; i < 4; i++) {
                int m = m0 + wy * 64 + i * 16 + quad * 4;
                int batch = m >> 11, s = m & 2047;
                u32x2 pk;
                pk[0] = pack_bf16_rne(acc[i][j][0] + bb, acc[i][j][1] + bb);
                pk[1] = pack_bf16_rne(acc[i][j][2] + bb, acc[i][j][3] + bb);
                *(u32x2*)(VTo + (((size_t)batch * 16 + h) * 64 + e) * 2048 + s) = pk;
            }
        } else {
            const float* bias = (proj == 0) ? bq : bk;
            unsigned short* dst = (proj == 0) ? Qo : Ko;
            float bb = bias[rem];
            float scl = (proj == 0) ? QSCALE : 1.0f;
#pragma unroll
            for (int i = 0; i < 4; i++) {
#pragma unroll
                for (int r = 0; r < 4; r++) {
                    int m = m0 + wy * 64 + i * 16 + quad * 4 + r;
                    int batch = m >> 11, s = m & 2047;
                    dst[(((size_t)batch * 16 + h) * 2048 + s) * 64 + e] = f2bf((acc[i][j][r] + bb) * scl);
                }
            }
        }
    }
}

__global__ __launch_bounds__(256) void gemm_out_kernel(
    const unsigned short* __restrict__ A, const unsigned short* __restrict__ BT,
    const float* __restrict__ bo, float* __restrict__ out) {
    __shared__ unsigned short As[2 * 128 * 32];
    __shared__ unsigned short Bs[2 * 128 * 32];
    const int tid = threadIdx.x;
    const int m0 = blockIdx.y * 128, n0 = blockIdx.x * 128;
    const int w = tid >> 6, lane = tid & 63, lr = lane & 15, quad = lane >> 4;
    const int wy = w >> 1, wx = w & 1;
    f32x4 acc[4][4];
#pragma unroll
    for (int i = 0; i < 4; i++)
#pragma unroll
        for (int j = 0; j < 4; j++) acc[i][j] = (f32x4){0.f, 0.f, 0.f, 0.f};
    const int drow = lane >> 2;
    const int dchunk = (lane & 3) ^ (drow & 3);
    const unsigned short* gA = A + (size_t)(m0 + w * 32 + drow) * 1024 + dchunk * 8;
    const unsigned short* gB = BT + (size_t)(n0 + w * 32 + drow) * 1024 + dchunk * 8;
    const int swav = (w * 32) * 32;
    const int fcol = (quad ^ (lr & 3)) * 8;
    dma16(gA, As + swav);
    dma16(gA + 16 * 1024, As + swav + 16 * 32);
    dma16(gB, Bs + swav);
    dma16(gB + 16 * 1024, Bs + swav + 16 * 32);
    for (int k0 = 0; k0 < 1024; k0 += 32) {
        const int cur = (k0 >> 5) & 1;
        const unsigned short* cA = As + cur * 4096;
        const unsigned short* cB = Bs + cur * 4096;
        pipeline_barrier();
        bf16x8 af[4], bfr[4];
#pragma unroll
        for (int i = 0; i < 4; i++) af[i] = ldfrag(cA + (wy * 64 + i * 16 + lr) * 32 + fcol);
#pragma unroll
        for (int j = 0; j < 4; j++) bfr[j] = ldfrag(cB + (wx * 64 + j * 16 + lr) * 32 + fcol);
        if (k0 + 32 < 1024) {
            const int nb = (cur ^ 1) * 4096 + swav;
            dma16(gA + k0 + 32, As + nb);
            dma16(gA + k0 + 32 + 16 * 1024, As + nb + 16 * 32);
            dma16(gB + k0 + 32, Bs + nb);
            dma16(gB + k0 + 32 + 16 * 1024, Bs + nb + 16 * 32);
        }
#pragma unroll
        for (int i = 0; i < 4; i++)
#pragma unroll
            for (int j = 0; j < 4; j++) acc[i][j] = MFMA_BF16(af[i], bfr[j], acc[i][j]);
    }
#pragma unroll
    for (int j = 0; j < 4; j++) {
        int n = n0 + wx * 64 + j * 16 + lr;
        float bb = bo[n];
#pragma unroll
        for (int i = 0; i < 4; i++) {
#pragma unroll
            for (int r = 0; r < 4; r++) {
                int m = m0 + wy * 64 + i * 16 + quad * 4 + r;
                out[(size_t)m * 1024 + n] = acc[i][j][r] + bb;
            }
        }
    }
}

// ---------------- flash attention (S^T = K Q^T, no-max softmax, dbuf DMA pipeline) ----------------
// EXACT R2 structure (94.9 µs champion) + ONE additive change: s_setprio(1/0) around the
// two MFMA clusters (T5). R2 runs 2 independent blocks/CU at staggered phases — the m191
// regime where setprio measurably pays (unlike lockstep GEMM, m190-null). Attributable:
// attn dur_us vs 94.9 baseline; everything else must match R2's counters exactly
// (VGPR 108, LDS 65536, conflicts 4.19M, FETCH 24.6 MB).
// P buffer: wave-private 64x64 u16, 16B-chunk XOR swizzle (chunk ^ (row&7)).
// K/V tiles: [2][64][64] u16, source-swizzled: LDS(r,c) = global(r, c ^ (r&7));
// frag reads use chunk (kc*4+quad) ^ (lr&7) -> <=2-way (free) b128.
__global__ __launch_bounds__(256, 2) void attn_fa_kernel(
    const unsigned short* __restrict__ Q, const unsigned short* __restrict__ K,
    const unsigned short* __restrict__ VT, unsigned short* __restrict__ Out) {
    __shared__ unsigned short Ks[2 * 64 * 64];
    __shared__ unsigned short Vs[2 * 64 * 64];
    __shared__ unsigned short Ps[256 * 64];  // wave-private 64-row P regions, XOR-swizzled
    const int bh = blockIdx.x;               // bh on x: all 8 q-blocks of a head share an XCD (id%8)
    const int q0 = blockIdx.y * 256;
    const int tid = threadIdx.x;
    const int w = tid >> 6, lane = tid & 63, lr = lane & 15, quad = lane >> 4;
    const unsigned short* Qh = Q + (size_t)bh * 2048 * 64;
    const unsigned short* Kh = K + (size_t)bh * 2048 * 64;
    const unsigned short* Vh = VT + (size_t)bh * 64 * 2048;

    const f32x4 ZERO4 = {0.f, 0.f, 0.f, 0.f};

    // DMA setup: wave w covers K/V rows w*16 .. w*16+15 (2 instrs of 8 rows each)
    const int drow = lane >> 3;
    const int dchunk = (lane & 7) ^ drow;
    const unsigned short* gK = Kh + (size_t)(w * 16 + drow) * 64 + dchunk * 8;
    const unsigned short* gV = Vh + (size_t)(w * 16 + drow) * 2048 + dchunk * 8;
    const int swav = (w * 16) * 64;
    // prologue: tile 0 -> buf 0
    dma16(gK, Ks + swav);
    dma16(gK + 8 * 64, Ks + swav + 8 * 64);
    dma16(gV, Vs + swav);
    dma16(gV + 8 * 2048, Vs + swav + 8 * 64);

    // Q fragments direct from global (one-time load; stays in regs)
    bf16x8 qb[4][2];  // [q-16-group][kc]
#pragma unroll
    for (int nt = 0; nt < 4; nt++)
#pragma unroll
        for (int kc = 0; kc < 2; kc++)
            qb[nt][kc] = ldfrag(Qh + (size_t)(q0 + w * 64 + nt * 16 + lr) * 64 + kc * 32 + quad * 8);

    f32x4 o[4][4];
#pragma unroll
    for (int i = 0; i < 4; i++)
#pragma unroll
        for (int j = 0; j < 4; j++) o[i][j] = ZERO4;
    float lp[4] = {0.f, 0.f, 0.f, 0.f};

    unsigned short* const Pw = Ps + (w * 64) * 64;  // this wave's private P rows
    const int swzb = lr & 7;                        // row&7 for all P rows this lane touches

    for (int t0 = 0; t0 < 2048; t0 += 64) {
        const int cur = (t0 >> 6) & 1;
        const unsigned short* cK = Ks + cur * 4096;
        const unsigned short* cV = Vs + cur * 4096;
        pipeline_barrier();  // drains this tile's DMA; releases other buffer
        // hoist ALL K/V fragment reads before the prefetch DMA issue
        bf16x8 ka[2][4], vb[2][4];
#pragma unroll
        for (int kc = 0; kc < 2; kc++)
#pragma unroll
            for (int mt = 0; mt < 4; mt++) {
                int fc = ((kc * 4 + quad) ^ swzb) * 8;
                ka[kc][mt] = ldfrag(cK + (mt * 16 + lr) * 64 + fc);
                vb[kc][mt] = ldfrag(cV + (mt * 16 + lr) * 64 + fc);
            }
        if (t0 + 64 < 2048) {  // prefetch next tile into other buffer
            const int nb = (cur ^ 1) * 4096 + swav;
            dma16(gK + (size_t)(t0 + 64) * 64, Ks + nb);
            dma16(gK + (size_t)(t0 + 64) * 64 + 8 * 64, Ks + nb + 8 * 64);
            dma16(gV + t0 + 64, Vs + nb);
            dma16(gV + t0 + 64 + 8 * 2048, Vs + nb + 8 * 64);
        }

        // S^T = K·Q^T, per-mt (16 t-rows): MFMA pair -> exp2 -> pack -> P write.
#pragma unroll
        for (int mt = 0; mt < 4; mt++) {
            f32x4 sc[4];
            __builtin_amdgcn_s_setprio(1);
#pragma unroll
            for (int nt = 0; nt < 4; nt++) {
                f32x4 z = ZERO4;
                sc[nt] = MFMA_BF16(ka[0][mt], qb[nt][0], z);
                sc[nt] = MFMA_BF16(ka[1][mt], qb[nt][1], sc[nt]);
            }
            __builtin_amdgcn_s_setprio(0);
#pragma unroll
            for (int nt = 0; nt < 4; nt++) {
                float p0 = fast_exp2(sc[nt][0]);
                float p1 = fast_exp2(sc[nt][1]);
                float p2 = fast_exp2(sc[nt][2]);
                float p3 = fast_exp2(sc[nt][3]);
                lp[nt] += (p0 + p1) + (p2 + p3);
                u32x2 pk;
                pk[0] = pack_bf16(p0, p1);
                pk[1] = pack_bf16(p2, p3);
                // row = nt*16+lr; 16B chunk (2*mt + quad/2) swizzled by row&7; 8B half = quad&1
                *(u32x2*)(Pw + (nt * 16 + lr) * 64 + ((2 * mt + (quad >> 1)) ^ swzb) * 8 +
                          (quad & 1) * 4) = pk;
            }
        }

        // O += P·V  (A = own-wave P rows — wave-private region, lgkm-ordered)
#pragma unroll
        for (int kc = 0; kc < 2; kc++) {
            const int fc = ((kc * 4 + quad) ^ swzb) * 8;
            __builtin_amdgcn_s_setprio(1);
#pragma unroll
            for (int g = 0; g < 4; g++) {
                bf16x8 pa = ldfrag(Pw + (g * 16 + lr) * 64 + fc);
                o[g][0] = MFMA_BF16(pa, vb[kc][0], o[g][0]);
                o[g][1] = MFMA_BF16(pa, vb[kc][1], o[g][1]);
                o[g][2] = MFMA_BF16(pa, vb[kc][2], o[g][2]);
                o[g][3] = MFMA_BF16(pa, vb[kc][3], o[g][3]);
            }
            __builtin_amdgcn_s_setprio(0);
        }
    }

    // final denominator: reduce across the 4 quads
#pragma unroll
    for (int g = 0; g < 4; g++) {
        float l = lp[g];
        l += __shfl_xor(l, 16, 64);
        l += __shfl_xor(l, 32, 64);
        lp[g] = l;
    }

    // normalize + write attn [B,S,H*E] bf16
    const int h = bh & 15, b = bh >> 4;
#pragma unroll
    for (int g = 0; g < 4; g++) {
#pragma unroll
        for (int r = 0; r < 4; r++) {
            float l = __shfl(lp[g], quad * 4 + r, 16);
            float inv = 1.0f / l;
            int s = q0 + w * 64 + g * 16 + quad * 4 + r;
#pragma unroll
            for (int et = 0; et < 4; et++) {
                int col = h * 64 + et * 16 + lr;
                Out[((size_t)(b * 2048 + s)) * 1024 + col] = f2bf(o[g][et][r] * inv);
            }
        }
    }
}

// ---------------- launch ----------------

extern "C" void kernel_launch(void* const* d_in, const int* in_sizes, int n_in,
                              void* d_out, int out_size, void* d_ws, size_t ws_size,
                              hipStream_t stream) {
    const float* x  = (const float*)d_in[0];
    const float* Wq = (const float*)d_in[1];
    const float* bq = (const float*)d_in[2];
    const float* Wk = (const float*)d_in[3];
    const float* bk = (const float*)d_in[4];
    const float* Wv = (const float*)d_in[5];
    const float* bv = (const float*)d_in[6];
    const float* Wo = (const float*)d_in[7];
    const float* bo = (const float*)d_in[8];
    float* out = (float*)d_out;

    char* ws = (char*)d_ws;
    unsigned short* xb    = (unsigned short*)(ws);              // 16 MiB; reused as attn buffer
    unsigned short* WqkvT = (unsigned short*)(ws + 16777216);   // 6 MiB
    unsigned short* WoT   = (unsigned short*)(ws + 23068672);   // 2 MiB
    unsigned short* Qb    = (unsigned short*)(ws + 25165824);   // 16 MiB
    unsigned short* Kb    = (unsigned short*)(ws + 41943040);   // 16 MiB
    unsigned short* VTb   = (unsigned short*)(ws + 58720256);   // 16 MiB (total 72 MiB)
    unsigned short* attn  = xb;  // xb is dead after gemm_qkv

    cvt_fused_kernel<<<dim3(6144), dim3(256), 0, stream>>>(x, Wq, Wk, Wv, Wo, xb, WqkvT, WoT);
    gemm_qkv_kernel<<<dim3(24, 64), dim3(256), 0, stream>>>(xb, WqkvT, bq, bk, bv, Qb, Kb, VTb);
    attn_fa_kernel<<<dim3(64, 8), dim3(256), 0, stream>>>(Qb, Kb, VTb, attn);
    gemm_out_kernel<<<dim3(8, 64), dim3(256), 0, stream>>>(attn, WoT, bo, out);
}